// Round 7
// baseline (714.792 us; speedup 1.0000x reference)
//
#include <hip/hip_runtime.h>
#include <hip/hip_bf16.h>

#define N_HID 128
#define BSH 9
#define BNODES 512          // nodes per bucket (1 << BSH)
#define CAP 14848           // LDS colx staging cap per bucket (58 KB)
#define CHUNK 4096          // edges per k_bucket block

typedef int   vint4  __attribute__((ext_vector_type(4)));
typedef float vflt4  __attribute__((ext_vector_type(4)));

// ---------------- bucketed CSR build ----------------

// block 0: zero gcount; block 1: zero dummy row n of all 16 HHc planes
__global__ void k_init(int* gcount, int nbk, float* HHc, int n, size_t PSH) {
    int t = threadIdx.x;
    if (blockIdx.x == 0) {
        if (t < nbk) gcount[t] = 0;
    } else {
        if (t < 128) {  // 16 planes x 8 lanes
            int p = t >> 3, l = t & 7;
            HHc[(size_t)p * PSH + (size_t)n * 8 + l] = 0.f;
        }
    }
}

// count edges per dst-bucket (LDS-privatized)
__global__ __launch_bounds__(256) void k_bcount(const int* __restrict__ dst,
                                                int E, int n, int* __restrict__ gcount) {
    __shared__ int hist[256];
    int t = threadIdx.x;
    hist[t] = 0;
    __syncthreads();
    long base = (long)blockIdx.x * CHUNK;
    long T = (long)E + n;
    int cnt = (int)min((long)CHUNK, T - base);
    for (int j = t; j < cnt; j += 256) {
        long i = base + j;
        int d = (i < E) ? dst[i] : (int)(i - E);
        atomicAdd(&hist[d >> BSH], 1);
    }
    __syncthreads();
    if (hist[t] > 0) atomicAdd(&gcount[t], hist[t]);
}

// exclusive scan of bucket counts -> gbase0, init gcur
__global__ void k_bscan(const int* __restrict__ gcount, int* __restrict__ gbase0,
                        int* __restrict__ gcur, int nbk) {
    __shared__ int s[256];
    int t = threadIdx.x;
    int v = (t < nbk) ? gcount[t] : 0;
    s[t] = v;
    __syncthreads();
    for (int off = 1; off < 256; off <<= 1) {
        int y = (t >= off) ? s[t - off] : 0;
        __syncthreads();
        s[t] += y;
        __syncthreads();
    }
    if (t < nbk) { gbase0[t] = s[t] - v; gcur[t] = s[t] - v; }
}

// partition edges into bucket-contiguous bpair[] (packed u32: src<<9 | dst_local)
__global__ __launch_bounds__(256) void k_bucket(const int* __restrict__ src,
                                                const int* __restrict__ dst,
                                                int E, int n, int* __restrict__ gcur,
                                                unsigned* __restrict__ bpair) {
    __shared__ int hist[256];
    __shared__ int incl[256];
    __shared__ int loff[256];
    __shared__ int gb[256];
    __shared__ unsigned lp[CHUNK];
    __shared__ unsigned char pb[CHUNK];
    int t = threadIdx.x;
    hist[t] = 0;
    __syncthreads();
    long base = (long)blockIdx.x * CHUNK;
    long T = (long)E + n;
    int cnt = (int)min((long)CHUNK, T - base);

    unsigned w_[16];
    int b_[16], r_[16];
    #pragma unroll
    for (int u = 0; u < 16; ++u) {
        int j = t + u * 256;
        if (j < cnt) {
            long i = base + j;
            int s, d;
            if (i < E) { s = src[i]; d = dst[i]; } else { s = (int)(i - E); d = s; }
            w_[u] = ((unsigned)s << BSH) | (unsigned)(d & (BNODES - 1));
            b_[u] = d >> BSH;
            r_[u] = atomicAdd(&hist[b_[u]], 1);
        } else { w_[u] = 0; b_[u] = 0; r_[u] = -1; }
    }
    __syncthreads();
    incl[t] = hist[t];
    __syncthreads();
    for (int off = 1; off < 256; off <<= 1) {
        int y = (t >= off) ? incl[t - off] : 0;
        __syncthreads();
        incl[t] += y;
        __syncthreads();
    }
    loff[t] = incl[t] - hist[t];
    if (hist[t] > 0) gb[t] = atomicAdd(&gcur[t], hist[t]);
    __syncthreads();
    #pragma unroll
    for (int u = 0; u < 16; ++u) {
        if (r_[u] >= 0) {
            int p = loff[b_[u]] + r_[u];
            lp[p] = w_[u];
            pb[p] = (unsigned char)b_[u];
        }
    }
    __syncthreads();
    for (int p = t; p < cnt; p += 256) {
        int b = pb[p];
        bpair[(size_t)gb[b] + (p - loff[b])] = lp[p];
    }
}

// per-bucket: degree hist -> dinv, local padded-offset scan -> lofs, bucket total -> psum
__global__ __launch_bounds__(256) void k_bdeg(const unsigned* __restrict__ bpair,
                                              const int* __restrict__ gbase0,
                                              const int* __restrict__ gcount,
                                              float* __restrict__ dinv,
                                              int* __restrict__ lofs,
                                              int* __restrict__ psum, int n) {
    __shared__ int hist[BNODES];
    __shared__ int sc[256];
    int b = blockIdx.x, t = threadIdx.x;
    hist[t] = 0; hist[t + 256] = 0;
    __syncthreads();
    int gs = gbase0[b], ge = gs + gcount[b];
    for (int e = gs + t; e < ge; e += 256)
        atomicAdd(&hist[bpair[e] & (BNODES - 1)], 1);
    __syncthreads();
    int q0 = 2 * t, q1 = 2 * t + 1;
    int p0 = (hist[q0] + 3) & ~3;
    int p1 = (hist[q1] + 3) & ~3;
    int pair = p0 + p1;
    sc[t] = pair;
    __syncthreads();
    for (int off = 1; off < 256; off <<= 1) {
        int y = (t >= off) ? sc[t - off] : 0;
        __syncthreads();
        sc[t] += y;
        __syncthreads();
    }
    int excl = sc[t] - pair;
    int first = b << BSH;
    if (first + q0 < n) {
        lofs[first + q0] = excl;
        dinv[first + q0] = rsqrtf((float)hist[q0]);
    }
    if (first + q1 < n) {
        lofs[first + q1] = excl + p0;
        dinv[first + q1] = rsqrtf((float)hist[q1]);
    }
    if (t == 255) psum[b] = sc[255];
}

// scan bucket padded totals -> pbase; write rptr[n]
__global__ void k_pscan(const int* __restrict__ psum, int* __restrict__ pbase,
                        int* __restrict__ rptr, int n, int nbk) {
    __shared__ int s[256];
    int t = threadIdx.x;
    int v = (t < nbk) ? psum[t] : 0;
    s[t] = v;
    __syncthreads();
    for (int off = 1; off < 256; off <<= 1) {
        int y = (t >= off) ? s[t - off] : 0;
        __syncthreads();
        s[t] += y;
        __syncthreads();
    }
    if (t < nbk) pbase[t] = s[t] - v;
    if (t == nbk - 1) rptr[n] = s[t];
}

// per-bucket CSR fill: LDS scatter (pad slots -> dummy node n), write rptr + colx
__global__ __launch_bounds__(256) void k_bfill(const unsigned* __restrict__ bpair,
                                               const int* __restrict__ gbase0,
                                               const int* __restrict__ gcount,
                                               const int* __restrict__ pbase,
                                               const int* __restrict__ lofs,
                                               const int* __restrict__ psum,
                                               int* __restrict__ rptr,
                                               int* __restrict__ colx, int n) {
    __shared__ int cur[BNODES];
    __shared__ int lcol[CAP];
    int b = blockIdx.x, t = threadIdx.x;
    int first = b << BSH;
    int base = pbase[b];
    int tot = min(psum[b], CAP);
    int lim = min(BNODES, n - first);
    for (int q = t; q < lim; q += 256) {
        int lo = lofs[first + q];
        cur[q] = lo;
        rptr[first + q] = base + lo;
    }
    for (int p = t; p < tot; p += 256) lcol[p] = n;
    __syncthreads();
    int gs = gbase0[b], ge = gs + gcount[b];
    for (int e = gs + t; e < ge; e += 256) {
        unsigned w = bpair[e];
        int lpos = atomicAdd(&cur[w & (BNODES - 1)], 1);
        if (lpos < CAP) lcol[lpos] = (int)(w >> BSH);
    }
    __syncthreads();
    for (int p = t; p < tot; p += 256) colx[base + p] = lcol[p];
}

// ---------------- dense GEMM: HHc[16 planes of 8 cols] = scale[.] * (A @ W) --------
// AL=0: A row-major [M][128].  AL=1: A = 16 ACT planes (stride PSA) in actBuf.

template<int AL>
__global__ __launch_bounds__(256) void k_gemm(const float* __restrict__ A,
                                              const float* __restrict__ actBuf,
                                              const float* __restrict__ W,
                                              const float* __restrict__ scale,
                                              float* __restrict__ HHc,
                                              int M, size_t PSH, size_t PSA) {
    __shared__ float As[32][132];
    __shared__ float Ws[32 * 128];   // repacked: [kk][h(2)][tx(16)][j(4)]
    int tid = threadIdx.x;
    int tx = tid & 15;
    int ty = tid >> 4;
    int bm = blockIdx.x * 128;
    float acc[8][8] = {};

    for (int k0 = 0; k0 < 128; k0 += 32) {
        #pragma unroll
        for (int it = 0; it < 4; ++it) {
            int idx = it * 256 + tid;
            int row = idx >> 3;
            int kq  = idx & 7;
            int grow = bm + row;
            vflt4 v = {0.f, 0.f, 0.f, 0.f};
            if (grow < M) {
                if (AL == 0) {
                    v = *(const vflt4*)(A + (size_t)grow * 128 + k0 + kq * 4);
                } else {
                    int kc = k0 + kq * 4;
                    v = *(const vflt4*)(actBuf + (size_t)(kc >> 3) * PSA
                                        + (size_t)grow * 8 + (kc & 7));
                }
            }
            As[kq * 4 + 0][row] = v.x;
            As[kq * 4 + 1][row] = v.y;
            As[kq * 4 + 2][row] = v.z;
            As[kq * 4 + 3][row] = v.w;
        }
        #pragma unroll
        for (int it = 0; it < 4; ++it) {
            int idx = it * 256 + tid;
            int kk = idx >> 5;
            int q  = idx & 31;
            vflt4 v = *(const vflt4*)(W + (size_t)(k0 + kk) * 128 + q * 4);
            *(vflt4*)&Ws[kk * 128 + ((q & 1) << 6) + ((q >> 1) << 2)] = v;
        }
        __syncthreads();
        #pragma unroll
        for (int kk = 0; kk < 32; ++kk) {
            float a[8], w[8];
            *(vflt4*)&a[0] = *(const vflt4*)&As[kk][ty * 8];
            *(vflt4*)&a[4] = *(const vflt4*)&As[kk][ty * 8 + 4];
            *(vflt4*)&w[0] = *(const vflt4*)&Ws[kk * 128 + tx * 4];
            *(vflt4*)&w[4] = *(const vflt4*)&Ws[kk * 128 + 64 + tx * 4];
            #pragma unroll
            for (int i = 0; i < 8; ++i)
                #pragma unroll
                for (int j = 0; j < 8; ++j)
                    acc[i][j] = fmaf(a[i], w[j], acc[i][j]);
        }
        __syncthreads();
    }
    // epilogue: cols tx*8..tx*8+7 == plane tx (8 cols/plane)
    float* ob = HHc + (size_t)tx * PSH;
    #pragma unroll
    for (int i = 0; i < 8; ++i) {
        int grow = bm + ty * 8 + i;
        if (grow < M) {
            float di = scale[grow];
            vflt4 o0, o1;
            o0.x = acc[i][0] * di; o0.y = acc[i][1] * di;
            o0.z = acc[i][2] * di; o0.w = acc[i][3] * di;
            o1.x = acc[i][4] * di; o1.y = acc[i][5] * di;
            o1.z = acc[i][6] * di; o1.w = acc[i][7] * di;
            *(vflt4*)(ob + (size_t)grow * 8)     = o0;
            *(vflt4*)(ob + (size_t)grow * 8 + 4) = o1;
        }
    }
}

// ---------------- SpMM aggregate, 8-col feature chunks, XCD-bound, 2-phase ----------------
// chunk = (blockIdx&7) + phase*8: one 3.2 MB plane per XCD per launch (fits 4 MB L2).
// 8 lanes per node. FINAL=0: write ACT planes (stride PSA); FINAL=1: row-major out.

template<int FINAL>
__global__ __launch_bounds__(256) void k_spmm(const float* __restrict__ HHc,
                                              const int* __restrict__ colx,
                                              const int* __restrict__ rptr,
                                              const float* __restrict__ dinv,
                                              const float* __restrict__ bias,
                                              float* __restrict__ actBuf,
                                              float* __restrict__ out,
                                              int n, size_t PSH, size_t PSA,
                                              int phase, int do_relu) {
    int chunk = (blockIdx.x & 7) + (phase << 3);
    int node  = (blockIdx.x >> 3) * 32 + (threadIdx.x >> 3);
    int ll    = threadIdx.x & 7;
    if (node >= n) return;
    const float* plane = HHc + (size_t)chunk * PSH + ll;
    int e  = rptr[node];
    int e1 = rptr[node + 1];
    float acc = 0.f;
    #pragma unroll 2
    for (; e < e1; e += 4) {
        vint4 s = *(const vint4*)(colx + e);
        float h0 = plane[s.x << 3];
        float h1 = plane[s.y << 3];
        float h2 = plane[s.z << 3];
        float h3 = plane[s.w << 3];
        acc += (h0 + h1) + (h2 + h3);
    }
    float o = fmaf(dinv[node], acc, bias[chunk * 8 + ll]);
    if (do_relu) o = fmaxf(o, 0.f);
    if (FINAL) {
        out[(size_t)node * 128 + chunk * 8 + ll] = o;
    } else {
        actBuf[(size_t)chunk * PSA + (size_t)node * 8 + ll] = o;
    }
}

// ---------------- host ----------------

extern "C" void kernel_launch(void* const* d_in, const int* in_sizes, int n_in,
                              void* d_out, int out_size, void* d_ws, size_t ws_size,
                              hipStream_t stream) {
    const float* x  = (const float*)d_in[0];
    const int*   ei = (const int*)d_in[1];
    const float* W1 = (const float*)d_in[2];
    const float* b1 = (const float*)d_in[3];
    const float* W2 = (const float*)d_in[4];
    const float* b2 = (const float*)d_in[5];
    const float* W3 = (const float*)d_in[6];
    const float* b3 = (const float*)d_in[7];
    float* out = (float*)d_out;

    const int n = in_sizes[0] / N_HID;        // 100000
    const int E = in_sizes[1] / 2;            // 1600000
    const long T = (long)E + n;
    const size_t PSH = (size_t)(n + 1) * 8;   // HHc plane stride (dummy row n)
    const size_t PSA = (size_t)n * 8;         // ACT plane stride (no dummy row)

    const int* src = ei;
    const int* dst = ei + E;

    size_t off = 0;
    auto alloc = [&](size_t bytes) {
        size_t o = off;
        off += (bytes + 255) & ~(size_t)255;
        return (char*)d_ws + o;
    };
    float* dinv   = (float*)alloc((size_t)n * 4);
    int*   rptr   = (int*)  alloc((size_t)(n + 1) * 4);
    int*   lofs   = (int*)  alloc((size_t)n * 4);
    int*   gcount = (int*)  alloc(1024);
    int*   gbase0 = (int*)  alloc(1024);
    int*   gcur   = (int*)  alloc(1024);
    int*   psum   = (int*)  alloc(1024);
    int*   pbase  = (int*)  alloc(1024);
    int*   colx   = (int*)  alloc((size_t)(T + 3 * (size_t)n + 64) * 4);
    float* HHc    = (float*)alloc(PSH * 16 * 4);   // 16 chunked GEMM-output planes
    // bpair (u32, 6.8 MB) aliases HHc front (consumed by k_bfill before gemm1)
    unsigned* bpair = (unsigned*)HHc;
    float* actBuf = out;   // 16 ACT planes x n*8 floats == out_size exactly
    (void)ws_size;

    const int NBK  = (n + BNODES - 1) >> BSH;          // 196 buckets
    const int ABLK = (int)((T + CHUNK - 1) / CHUNK);   // 416 chunks

    k_init<<<2, 256, 0, stream>>>(gcount, NBK, HHc, n, PSH);
    k_bcount<<<ABLK, 256, 0, stream>>>(dst, E, n, gcount);
    k_bscan<<<1, 256, 0, stream>>>(gcount, gbase0, gcur, NBK);
    k_bucket<<<ABLK, 256, 0, stream>>>(src, dst, E, n, gcur, bpair);
    k_bdeg<<<NBK, 256, 0, stream>>>(bpair, gbase0, gcount, dinv, lofs, psum, n);
    k_pscan<<<1, 256, 0, stream>>>(psum, pbase, rptr, n, NBK);
    k_bfill<<<NBK, 256, 0, stream>>>(bpair, gbase0, gcount, pbase, lofs, psum, rptr, colx, n);
    // re-zero HHc dummy rows (bpair alias clobbered them)
    k_init<<<2, 256, 0, stream>>>(gcount, 0, HHc, n, PSH);

    int gblk = (n + 127) / 128;
    int sblk = 8 * ((n + 31) / 32);   // 8 chunks x node groups of 32

    k_gemm<0><<<gblk, 256, 0, stream>>>(x, nullptr, W1, dinv, HHc, n, PSH, PSA);
    k_spmm<0><<<sblk, 256, 0, stream>>>(HHc, colx, rptr, dinv, b1, actBuf, out, n, PSH, PSA, 0, 1);
    k_spmm<0><<<sblk, 256, 0, stream>>>(HHc, colx, rptr, dinv, b1, actBuf, out, n, PSH, PSA, 1, 1);
    k_gemm<1><<<gblk, 256, 0, stream>>>(nullptr, actBuf, W2, dinv, HHc, n, PSH, PSA);
    k_spmm<0><<<sblk, 256, 0, stream>>>(HHc, colx, rptr, dinv, b2, actBuf, out, n, PSH, PSA, 0, 1);
    k_spmm<0><<<sblk, 256, 0, stream>>>(HHc, colx, rptr, dinv, b2, actBuf, out, n, PSH, PSA, 1, 1);
    k_gemm<1><<<gblk, 256, 0, stream>>>(nullptr, actBuf, W3, dinv, HHc, n, PSH, PSA);
    // FINAL layer: phase 0 writes cols 0-63, phase 1 cols 64-127 (row-major out).
    // ACT planes in out are fully consumed by gemm3 before these overwrite out.
    k_spmm<1><<<sblk, 256, 0, stream>>>(HHc, colx, rptr, dinv, b3, actBuf, out, n, PSH, PSA, 0, 0);
    k_spmm<1><<<sblk, 256, 0, stream>>>(HHc, colx, rptr, dinv, b3, actBuf, out, n, PSH, PSA, 1, 0);
}

// Round 8
// 641.984 us; speedup vs baseline: 1.1134x; 1.1134x over previous
//
#include <hip/hip_runtime.h>
#include <hip/hip_bf16.h>

#define N_HID 128
#define BSH 9
#define BNODES 512          // nodes per bucket (1 << BSH)
#define CAP 14848           // LDS colx staging cap per bucket (58 KB)
#define CHUNK 4096          // edges per k_bucket block

typedef int      vint4  __attribute__((ext_vector_type(4)));
typedef float    vflt4  __attribute__((ext_vector_type(4)));
typedef short    s16x8  __attribute__((ext_vector_type(8)));
typedef unsigned long long u64;

// ---------------- bucketed CSR build ----------------

// block 0: zero gcount; block 1: zero dummy row n of all 8 HHc planes (16 cols each)
__global__ void k_init(int* gcount, int nbk, float* HHc, int n, size_t PSH) {
    int t = threadIdx.x;
    if (blockIdx.x == 0) {
        if (t < nbk) gcount[t] = 0;
    } else {
        if (t < 128) {  // 8 planes x 16 lanes
            int p = t >> 4, l = t & 15;
            HHc[(size_t)p * PSH + (size_t)n * 16 + l] = 0.f;
        }
    }
}

// count edges per dst-bucket (LDS-privatized)
__global__ __launch_bounds__(256) void k_bcount(const int* __restrict__ dst,
                                                int E, int n, int* __restrict__ gcount) {
    __shared__ int hist[256];
    int t = threadIdx.x;
    hist[t] = 0;
    __syncthreads();
    long base = (long)blockIdx.x * CHUNK;
    long T = (long)E + n;
    int cnt = (int)min((long)CHUNK, T - base);
    for (int j = t; j < cnt; j += 256) {
        long i = base + j;
        int d = (i < E) ? dst[i] : (int)(i - E);
        atomicAdd(&hist[d >> BSH], 1);
    }
    __syncthreads();
    if (hist[t] > 0) atomicAdd(&gcount[t], hist[t]);
}

// exclusive scan of bucket counts -> gbase0, init gcur
__global__ void k_bscan(const int* __restrict__ gcount, int* __restrict__ gbase0,
                        int* __restrict__ gcur, int nbk) {
    __shared__ int s[256];
    int t = threadIdx.x;
    int v = (t < nbk) ? gcount[t] : 0;
    s[t] = v;
    __syncthreads();
    for (int off = 1; off < 256; off <<= 1) {
        int y = (t >= off) ? s[t - off] : 0;
        __syncthreads();
        s[t] += y;
        __syncthreads();
    }
    if (t < nbk) { gbase0[t] = s[t] - v; gcur[t] = s[t] - v; }
}

// partition edges into bucket-contiguous bpair[] (packed u32: src<<9 | dst_local)
__global__ __launch_bounds__(256) void k_bucket(const int* __restrict__ src,
                                                const int* __restrict__ dst,
                                                int E, int n, int* __restrict__ gcur,
                                                unsigned* __restrict__ bpair) {
    __shared__ int hist[256];
    __shared__ int incl[256];
    __shared__ int loff[256];
    __shared__ int gb[256];
    __shared__ unsigned lp[CHUNK];
    __shared__ unsigned char pb[CHUNK];
    int t = threadIdx.x;
    hist[t] = 0;
    __syncthreads();
    long base = (long)blockIdx.x * CHUNK;
    long T = (long)E + n;
    int cnt = (int)min((long)CHUNK, T - base);

    unsigned w_[16];
    int b_[16], r_[16];
    #pragma unroll
    for (int u = 0; u < 16; ++u) {
        int j = t + u * 256;
        if (j < cnt) {
            long i = base + j;
            int s, d;
            if (i < E) { s = src[i]; d = dst[i]; } else { s = (int)(i - E); d = s; }
            w_[u] = ((unsigned)s << BSH) | (unsigned)(d & (BNODES - 1));
            b_[u] = d >> BSH;
            r_[u] = atomicAdd(&hist[b_[u]], 1);
        } else { w_[u] = 0; b_[u] = 0; r_[u] = -1; }
    }
    __syncthreads();
    incl[t] = hist[t];
    __syncthreads();
    for (int off = 1; off < 256; off <<= 1) {
        int y = (t >= off) ? incl[t - off] : 0;
        __syncthreads();
        incl[t] += y;
        __syncthreads();
    }
    loff[t] = incl[t] - hist[t];
    if (hist[t] > 0) gb[t] = atomicAdd(&gcur[t], hist[t]);
    __syncthreads();
    #pragma unroll
    for (int u = 0; u < 16; ++u) {
        if (r_[u] >= 0) {
            int p = loff[b_[u]] + r_[u];
            lp[p] = w_[u];
            pb[p] = (unsigned char)b_[u];
        }
    }
    __syncthreads();
    for (int p = t; p < cnt; p += 256) {
        int b = pb[p];
        bpair[(size_t)gb[b] + (p - loff[b])] = lp[p];
    }
}

// per-bucket: degree hist -> dinv, local padded-offset scan -> lofs, bucket total -> psum
__global__ __launch_bounds__(256) void k_bdeg(const unsigned* __restrict__ bpair,
                                              const int* __restrict__ gbase0,
                                              const int* __restrict__ gcount,
                                              float* __restrict__ dinv,
                                              int* __restrict__ lofs,
                                              int* __restrict__ psum, int n) {
    __shared__ int hist[BNODES];
    __shared__ int sc[256];
    int b = blockIdx.x, t = threadIdx.x;
    hist[t] = 0; hist[t + 256] = 0;
    __syncthreads();
    int gs = gbase0[b], ge = gs + gcount[b];
    for (int e = gs + t; e < ge; e += 256)
        atomicAdd(&hist[bpair[e] & (BNODES - 1)], 1);
    __syncthreads();
    int q0 = 2 * t, q1 = 2 * t + 1;
    int p0 = (hist[q0] + 3) & ~3;
    int p1 = (hist[q1] + 3) & ~3;
    int pair = p0 + p1;
    sc[t] = pair;
    __syncthreads();
    for (int off = 1; off < 256; off <<= 1) {
        int y = (t >= off) ? sc[t - off] : 0;
        __syncthreads();
        sc[t] += y;
        __syncthreads();
    }
    int excl = sc[t] - pair;
    int first = b << BSH;
    if (first + q0 < n) {
        lofs[first + q0] = excl;
        dinv[first + q0] = rsqrtf((float)hist[q0]);
    }
    if (first + q1 < n) {
        lofs[first + q1] = excl + p0;
        dinv[first + q1] = rsqrtf((float)hist[q1]);
    }
    if (t == 255) psum[b] = sc[255];
}

// scan bucket padded totals -> pbase; write rptr[n]
__global__ void k_pscan(const int* __restrict__ psum, int* __restrict__ pbase,
                        int* __restrict__ rptr, int n, int nbk) {
    __shared__ int s[256];
    int t = threadIdx.x;
    int v = (t < nbk) ? psum[t] : 0;
    s[t] = v;
    __syncthreads();
    for (int off = 1; off < 256; off <<= 1) {
        int y = (t >= off) ? s[t - off] : 0;
        __syncthreads();
        s[t] += y;
        __syncthreads();
    }
    if (t < nbk) pbase[t] = s[t] - v;
    if (t == nbk - 1) rptr[n] = s[t];
}

// per-bucket CSR fill: LDS scatter (pad slots -> dummy node n), write rptr + colx
__global__ __launch_bounds__(256) void k_bfill(const unsigned* __restrict__ bpair,
                                               const int* __restrict__ gbase0,
                                               const int* __restrict__ gcount,
                                               const int* __restrict__ pbase,
                                               const int* __restrict__ lofs,
                                               const int* __restrict__ psum,
                                               int* __restrict__ rptr,
                                               int* __restrict__ colx, int n) {
    __shared__ int cur[BNODES];
    __shared__ int lcol[CAP];
    int b = blockIdx.x, t = threadIdx.x;
    int first = b << BSH;
    int base = pbase[b];
    int tot = min(psum[b], CAP);
    int lim = min(BNODES, n - first);
    for (int q = t; q < lim; q += 256) {
        int lo = lofs[first + q];
        cur[q] = lo;
        rptr[first + q] = base + lo;
    }
    for (int p = t; p < tot; p += 256) lcol[p] = n;
    __syncthreads();
    int gs = gbase0[b], ge = gs + gcount[b];
    for (int e = gs + t; e < ge; e += 256) {
        unsigned w = bpair[e];
        int lpos = atomicAdd(&cur[w & (BNODES - 1)], 1);
        if (lpos < CAP) lcol[lpos] = (int)(w >> BSH);
    }
    __syncthreads();
    for (int p = t; p < tot; p += 256) colx[base + p] = lcol[p];
}

// ---------------- W split: whT/wlT[n][k] bf16 (transposed), per layer ----------------

__global__ void k_wsplit(const float* __restrict__ W1, const float* __restrict__ W2,
                         const float* __restrict__ W3,
                         unsigned short* __restrict__ wh, unsigned short* __restrict__ wl) {
    int idx = blockIdx.x * 256 + threadIdx.x;     // 0..49151
    int l = idx >> 14;
    int r = idx & 16383;
    int k = r >> 7, nn = r & 127;
    const float* W = (l == 0) ? W1 : (l == 1) ? W2 : W3;
    float a = W[k * 128 + nn];
    unsigned ab = __float_as_uint(a);
    unsigned hb = (ab + 0x7fffu + ((ab >> 16) & 1)) & 0xffff0000u;
    float res = a - __uint_as_float(hb);
    unsigned rb = __float_as_uint(res);
    unsigned lb = (rb + 0x7fffu + ((rb >> 16) & 1)) >> 16;
    wh[l * 16384 + nn * 128 + k] = (unsigned short)(hb >> 16);
    wl[l * 16384 + nn * 128 + k] = (unsigned short)lb;
}

// ---------------- split-bf16 MFMA GEMM: HHc[8 planes of 16] = scale * (A @ W) --------
// C = ah*wh + ah*wl + al*wh (al*wl dropped, ~2^-18 rel).
// mfma_f32_16x16x32_bf16 frag layout: A: m=lane&15, k=(lane>>4)*4+(r&3)+16*(r>>2);
// B: n=lane&15, same k; C/D: col=lane&15, row=(lane>>4)*4+r (HW-verified).
// AL=0: A row-major [M][128].  AL=1: A = ACT planes (actD 0-6 + actS), 16 cols each.

__device__ __forceinline__ s16x8 ld_frag(const unsigned short* row, int klo) {
    union { u64 d[2]; s16x8 v; } u;
    u.d[0] = *(const u64*)(row + klo);
    u.d[1] = *(const u64*)(row + klo + 16);
    return u.v;
}

template<int AL>
__global__ __launch_bounds__(256) void k_gemm(const float* __restrict__ A,
                                              const float* __restrict__ actD,
                                              const float* __restrict__ actS,
                                              const unsigned short* __restrict__ whT,
                                              const unsigned short* __restrict__ wlT,
                                              const float* __restrict__ scale,
                                              float* __restrict__ HHc,
                                              int M, size_t PSH, size_t PSA) {
    __shared__ unsigned short Ah[128][32], Al[128][32];
    __shared__ unsigned short Wh[128][32], Wl[128][32];
    int tid = threadIdx.x;
    int w = tid >> 6, l = tid & 63;
    int bm = blockIdx.x * 128;
    vflt4 acc[2][8] = {};

    for (int kc = 0; kc < 128; kc += 32) {
        // stage A chunk -> Ah/Al (bf16 split)
        #pragma unroll
        for (int it = 0; it < 4; ++it) {
            int idx = it * 256 + tid;
            int row = idx >> 3, kseg = (idx & 7) * 4;
            int grow = bm + row;
            vflt4 v = {0.f, 0.f, 0.f, 0.f};
            if (grow < M) {
                if (AL == 0) {
                    v = *(const vflt4*)(A + (size_t)grow * 128 + kc + kseg);
                } else {
                    int kcol = kc + kseg;
                    int pl = kcol >> 4;
                    const float* ab = (pl < 7) ? (actD + (size_t)pl * PSA) : actS;
                    v = *(const vflt4*)(ab + (size_t)grow * 16 + (kcol & 15));
                }
            }
            #pragma unroll
            for (int j = 0; j < 4; ++j) {
                unsigned ab2 = __float_as_uint(v[j]);
                unsigned hb = (ab2 + 0x7fffu + ((ab2 >> 16) & 1)) & 0xffff0000u;
                float res = v[j] - __uint_as_float(hb);
                unsigned rb = __float_as_uint(res);
                unsigned lb = (rb + 0x7fffu + ((rb >> 16) & 1)) >> 16;
                Ah[row][kseg + j] = (unsigned short)(hb >> 16);
                Al[row][kseg + j] = (unsigned short)lb;
            }
        }
        // stage W chunk (pre-split, [n][k] layout) -> Wh/Wl
        #pragma unroll
        for (int it = 0; it < 4; ++it) {
            int idx = it * 256 + tid;
            int nn = idx >> 3, kseg = (idx & 7) * 4;
            *(u64*)&Wh[nn][kseg] = *(const u64*)(whT + nn * 128 + kc + kseg);
            *(u64*)&Wl[nn][kseg] = *(const u64*)(wlT + nn * 128 + kc + kseg);
        }
        __syncthreads();

        int klo = (l >> 4) * 4;
        s16x8 ah0 = ld_frag(Ah[w * 32 + (l & 15)],      klo);
        s16x8 ah1 = ld_frag(Ah[w * 32 + 16 + (l & 15)], klo);
        s16x8 al0 = ld_frag(Al[w * 32 + (l & 15)],      klo);
        s16x8 al1 = ld_frag(Al[w * 32 + 16 + (l & 15)], klo);
        #pragma unroll
        for (int tn = 0; tn < 8; ++tn) {
            s16x8 whf = ld_frag(Wh[tn * 16 + (l & 15)], klo);
            s16x8 wlf = ld_frag(Wl[tn * 16 + (l & 15)], klo);
            acc[0][tn] = __builtin_amdgcn_mfma_f32_16x16x32_bf16(ah0, whf, acc[0][tn], 0, 0, 0);
            acc[0][tn] = __builtin_amdgcn_mfma_f32_16x16x32_bf16(ah0, wlf, acc[0][tn], 0, 0, 0);
            acc[0][tn] = __builtin_amdgcn_mfma_f32_16x16x32_bf16(al0, whf, acc[0][tn], 0, 0, 0);
            acc[1][tn] = __builtin_amdgcn_mfma_f32_16x16x32_bf16(ah1, whf, acc[1][tn], 0, 0, 0);
            acc[1][tn] = __builtin_amdgcn_mfma_f32_16x16x32_bf16(ah1, wlf, acc[1][tn], 0, 0, 0);
            acc[1][tn] = __builtin_amdgcn_mfma_f32_16x16x32_bf16(al1, whf, acc[1][tn], 0, 0, 0);
        }
        __syncthreads();
    }
    // epilogue: tile (tm,tn): row = bm + w*32 + tm*16 + (l>>4)*4 + r, col = tn*16 + (l&15)
    #pragma unroll
    for (int tm = 0; tm < 2; ++tm) {
        #pragma unroll
        for (int tn = 0; tn < 8; ++tn) {
            float* ob = HHc + (size_t)tn * PSH + (l & 15);
            #pragma unroll
            for (int r = 0; r < 4; ++r) {
                int grow = bm + w * 32 + tm * 16 + (l >> 4) * 4 + r;
                if (grow < M) {
                    ob[(size_t)grow * 16] = acc[tm][tn][r] * scale[grow];
                }
            }
        }
    }
}

// ---------------- SpMM aggregate, 16-col feature chunks, XCD-bound (R6 design) --------
// chunk = blockIdx&7 -> plane per XCD. 16 lanes/node, scalar gathers (64 B/edge req).
// FINAL=0: write ACT planes (actD 0-6 + actS); FINAL=1: row-major out.

template<int FINAL>
__global__ __launch_bounds__(256) void k_spmm(const float* __restrict__ HHc,
                                              const int* __restrict__ colx,
                                              const int* __restrict__ rptr,
                                              const float* __restrict__ dinv,
                                              const float* __restrict__ bias,
                                              float* __restrict__ actD,
                                              float* __restrict__ actS,
                                              float* __restrict__ out,
                                              int n, size_t PSH, size_t PSA, int do_relu) {
    int chunk = blockIdx.x & 7;
    int node  = (blockIdx.x >> 3) * 16 + (threadIdx.x >> 4);
    int ll    = threadIdx.x & 15;
    if (node >= n) return;
    const float* plane = HHc + (size_t)chunk * PSH;
    int e  = rptr[node];
    int e1 = rptr[node + 1];
    float acc = 0.f;
    #pragma unroll 2
    for (; e < e1; e += 4) {
        vint4 s = *(const vint4*)(colx + e);
        float h0 = plane[(size_t)s.x * 16 + ll];
        float h1 = plane[(size_t)s.y * 16 + ll];
        float h2 = plane[(size_t)s.z * 16 + ll];
        float h3 = plane[(size_t)s.w * 16 + ll];
        acc += (h0 + h1) + (h2 + h3);
    }
    float o = fmaf(dinv[node], acc, bias[chunk * 16 + ll]);
    if (do_relu) o = fmaxf(o, 0.f);
    if (FINAL) {
        out[(size_t)node * 128 + chunk * 16 + ll] = o;
    } else {
        float* ob = (chunk < 7) ? (actD + (size_t)chunk * PSA) : actS;
        ob[(size_t)node * 16 + ll] = o;
    }
}

// ---------------- host ----------------

extern "C" void kernel_launch(void* const* d_in, const int* in_sizes, int n_in,
                              void* d_out, int out_size, void* d_ws, size_t ws_size,
                              hipStream_t stream) {
    const float* x  = (const float*)d_in[0];
    const int*   ei = (const int*)d_in[1];
    const float* W1 = (const float*)d_in[2];
    const float* b1 = (const float*)d_in[3];
    const float* W2 = (const float*)d_in[4];
    const float* b2 = (const float*)d_in[5];
    const float* W3 = (const float*)d_in[6];
    const float* b3 = (const float*)d_in[7];
    float* out = (float*)d_out;

    const int n = in_sizes[0] / N_HID;         // 100000
    const int E = in_sizes[1] / 2;             // 1600000
    const long T = (long)E + n;
    const size_t PSH = (size_t)(n + 1) * 16;   // HHc plane stride (dummy row n)
    const size_t PSA = (size_t)n * 16;         // ACT plane stride

    const int* src = ei;
    const int* dst = ei + E;

    size_t off = 0;
    auto alloc = [&](size_t bytes) {
        size_t o = off;
        off += (bytes + 255) & ~(size_t)255;
        return (char*)d_ws + o;
    };
    float* dinv   = (float*)alloc((size_t)n * 4);
    int*   rptr   = (int*)  alloc((size_t)(n + 1) * 4);
    int*   lofs   = (int*)  alloc((size_t)n * 4);
    int*   gcount = (int*)  alloc(1024);
    int*   gbase0 = (int*)  alloc(1024);
    int*   gcur   = (int*)  alloc(1024);
    int*   psum   = (int*)  alloc(1024);
    int*   pbase  = (int*)  alloc(1024);
    unsigned short* whT = (unsigned short*)alloc(3 * 16384 * 2);
    unsigned short* wlT = (unsigned short*)alloc(3 * 16384 * 2);
    int*   colx   = (int*)  alloc((size_t)(T + 3 * (size_t)n + 64) * 4);
    float* actS   = (float*)alloc(PSA * 4);        // ACT spill plane (chunk 7)
    float* HHc    = (float*)alloc(PSH * 8 * 4);    // 8 chunked GEMM-output planes
    // bpair (u32, 6.8 MB) aliases HHc front (consumed by k_bfill before gemm1)
    unsigned* bpair = (unsigned*)HHc;
    float* actD = out;   // ACT planes 0-6 staged in d_out
    (void)ws_size;

    const int NBK  = (n + BNODES - 1) >> BSH;          // 196 buckets
    const int ABLK = (int)((T + CHUNK - 1) / CHUNK);   // 416 chunks

    k_init<<<2, 256, 0, stream>>>(gcount, NBK, HHc, n, PSH);
    k_wsplit<<<192, 256, 0, stream>>>(W1, W2, W3, whT, wlT);
    k_bcount<<<ABLK, 256, 0, stream>>>(dst, E, n, gcount);
    k_bscan<<<1, 256, 0, stream>>>(gcount, gbase0, gcur, NBK);
    k_bucket<<<ABLK, 256, 0, stream>>>(src, dst, E, n, gcur, bpair);
    k_bdeg<<<NBK, 256, 0, stream>>>(bpair, gbase0, gcount, dinv, lofs, psum, n);
    k_pscan<<<1, 256, 0, stream>>>(psum, pbase, rptr, n, NBK);
    k_bfill<<<NBK, 256, 0, stream>>>(bpair, gbase0, gcount, pbase, lofs, psum, rptr, colx, n);
    // re-zero HHc dummy rows (bpair alias clobbered them)
    k_init<<<2, 256, 0, stream>>>(gcount, 0, HHc, n, PSH);

    int gblk = (n + 127) / 128;
    int sblk = 8 * ((n + 15) / 16);   // 8 chunks x node groups of 16

    k_gemm<0><<<gblk, 256, 0, stream>>>(x, nullptr, nullptr, whT, wlT, dinv, HHc, n, PSH, PSA);
    k_spmm<0><<<sblk, 256, 0, stream>>>(HHc, colx, rptr, dinv, b1, actD, actS, out, n, PSH, PSA, 1);
    k_gemm<1><<<gblk, 256, 0, stream>>>(nullptr, actD, actS, whT + 16384, wlT + 16384, dinv, HHc, n, PSH, PSA);
    k_spmm<0><<<sblk, 256, 0, stream>>>(HHc, colx, rptr, dinv, b2, actD, actS, out, n, PSH, PSA, 1);
    k_gemm<1><<<gblk, 256, 0, stream>>>(nullptr, actD, actS, whT + 32768, wlT + 32768, dinv, HHc, n, PSH, PSA);
    k_spmm<1><<<sblk, 256, 0, stream>>>(HHc, colx, rptr, dinv, b3, actD, actS, out, n, PSH, PSA, 0);
}

// Round 9
// 573.090 us; speedup vs baseline: 1.2473x; 1.1202x over previous
//
#include <hip/hip_runtime.h>
#include <hip/hip_bf16.h>

#define N_HID 128
#define BSH 9
#define BNODES 512          // nodes per bucket (1 << BSH)
#define CAP 14848           // LDS colx staging cap per bucket (58 KB)
#define CHUNK 4096          // edges per k_bucket block

typedef int      vint4  __attribute__((ext_vector_type(4)));
typedef float    vflt4  __attribute__((ext_vector_type(4)));
typedef short    s16x8  __attribute__((ext_vector_type(8)));
typedef unsigned long long u64;

// ---------------- bucketed CSR build ----------------

// block 0: zero gcount; block 1: zero dummy row n of all 8 HHc planes (16 cols each)
__global__ void k_init(int* gcount, int nbk, float* HHc, int n, size_t PSH) {
    int t = threadIdx.x;
    if (blockIdx.x == 0) {
        if (t < nbk) gcount[t] = 0;
    } else {
        if (t < 128) {  // 8 planes x 16 lanes
            int p = t >> 4, l = t & 15;
            HHc[(size_t)p * PSH + (size_t)n * 16 + l] = 0.f;
        }
    }
}

// count edges per dst-bucket (LDS-privatized)
__global__ __launch_bounds__(256) void k_bcount(const int* __restrict__ dst,
                                                int E, int n, int* __restrict__ gcount) {
    __shared__ int hist[256];
    int t = threadIdx.x;
    hist[t] = 0;
    __syncthreads();
    long base = (long)blockIdx.x * CHUNK;
    long T = (long)E + n;
    int cnt = (int)min((long)CHUNK, T - base);
    for (int j = t; j < cnt; j += 256) {
        long i = base + j;
        int d = (i < E) ? dst[i] : (int)(i - E);
        atomicAdd(&hist[d >> BSH], 1);
    }
    __syncthreads();
    if (hist[t] > 0) atomicAdd(&gcount[t], hist[t]);
}

// exclusive scan of bucket counts -> gbase0, init gcur
__global__ void k_bscan(const int* __restrict__ gcount, int* __restrict__ gbase0,
                        int* __restrict__ gcur, int nbk) {
    __shared__ int s[256];
    int t = threadIdx.x;
    int v = (t < nbk) ? gcount[t] : 0;
    s[t] = v;
    __syncthreads();
    for (int off = 1; off < 256; off <<= 1) {
        int y = (t >= off) ? s[t - off] : 0;
        __syncthreads();
        s[t] += y;
        __syncthreads();
    }
    if (t < nbk) { gbase0[t] = s[t] - v; gcur[t] = s[t] - v; }
}

// partition edges into bucket-contiguous bpair[] (packed u32: src<<9 | dst_local)
__global__ __launch_bounds__(256) void k_bucket(const int* __restrict__ src,
                                                const int* __restrict__ dst,
                                                int E, int n, int* __restrict__ gcur,
                                                unsigned* __restrict__ bpair) {
    __shared__ int hist[256];
    __shared__ int incl[256];
    __shared__ int loff[256];
    __shared__ int gb[256];
    __shared__ unsigned lp[CHUNK];
    __shared__ unsigned char pb[CHUNK];
    int t = threadIdx.x;
    hist[t] = 0;
    __syncthreads();
    long base = (long)blockIdx.x * CHUNK;
    long T = (long)E + n;
    int cnt = (int)min((long)CHUNK, T - base);

    unsigned w_[16];
    int b_[16], r_[16];
    #pragma unroll
    for (int u = 0; u < 16; ++u) {
        int j = t + u * 256;
        if (j < cnt) {
            long i = base + j;
            int s, d;
            if (i < E) { s = src[i]; d = dst[i]; } else { s = (int)(i - E); d = s; }
            w_[u] = ((unsigned)s << BSH) | (unsigned)(d & (BNODES - 1));
            b_[u] = d >> BSH;
            r_[u] = atomicAdd(&hist[b_[u]], 1);
        } else { w_[u] = 0; b_[u] = 0; r_[u] = -1; }
    }
    __syncthreads();
    incl[t] = hist[t];
    __syncthreads();
    for (int off = 1; off < 256; off <<= 1) {
        int y = (t >= off) ? incl[t - off] : 0;
        __syncthreads();
        incl[t] += y;
        __syncthreads();
    }
    loff[t] = incl[t] - hist[t];
    if (hist[t] > 0) gb[t] = atomicAdd(&gcur[t], hist[t]);
    __syncthreads();
    #pragma unroll
    for (int u = 0; u < 16; ++u) {
        if (r_[u] >= 0) {
            int p = loff[b_[u]] + r_[u];
            lp[p] = w_[u];
            pb[p] = (unsigned char)b_[u];
        }
    }
    __syncthreads();
    for (int p = t; p < cnt; p += 256) {
        int b = pb[p];
        bpair[(size_t)gb[b] + (p - loff[b])] = lp[p];
    }
}

// per-bucket: degree hist -> dinv, local padded-offset scan -> lofs, bucket total -> psum
__global__ __launch_bounds__(256) void k_bdeg(const unsigned* __restrict__ bpair,
                                              const int* __restrict__ gbase0,
                                              const int* __restrict__ gcount,
                                              float* __restrict__ dinv,
                                              int* __restrict__ lofs,
                                              int* __restrict__ psum, int n) {
    __shared__ int hist[BNODES];
    __shared__ int sc[256];
    int b = blockIdx.x, t = threadIdx.x;
    hist[t] = 0; hist[t + 256] = 0;
    __syncthreads();
    int gs = gbase0[b], ge = gs + gcount[b];
    for (int e = gs + t; e < ge; e += 256)
        atomicAdd(&hist[bpair[e] & (BNODES - 1)], 1);
    __syncthreads();
    int q0 = 2 * t, q1 = 2 * t + 1;
    int p0 = (hist[q0] + 3) & ~3;
    int p1 = (hist[q1] + 3) & ~3;
    int pair = p0 + p1;
    sc[t] = pair;
    __syncthreads();
    for (int off = 1; off < 256; off <<= 1) {
        int y = (t >= off) ? sc[t - off] : 0;
        __syncthreads();
        sc[t] += y;
        __syncthreads();
    }
    int excl = sc[t] - pair;
    int first = b << BSH;
    if (first + q0 < n) {
        lofs[first + q0] = excl;
        dinv[first + q0] = rsqrtf((float)hist[q0]);
    }
    if (first + q1 < n) {
        lofs[first + q1] = excl + p0;
        dinv[first + q1] = rsqrtf((float)hist[q1]);
    }
    if (t == 255) psum[b] = sc[255];
}

// scan bucket padded totals -> pbase; write rptr[n]
__global__ void k_pscan(const int* __restrict__ psum, int* __restrict__ pbase,
                        int* __restrict__ rptr, int n, int nbk) {
    __shared__ int s[256];
    int t = threadIdx.x;
    int v = (t < nbk) ? psum[t] : 0;
    s[t] = v;
    __syncthreads();
    for (int off = 1; off < 256; off <<= 1) {
        int y = (t >= off) ? s[t - off] : 0;
        __syncthreads();
        s[t] += y;
        __syncthreads();
    }
    if (t < nbk) pbase[t] = s[t] - v;
    if (t == nbk - 1) rptr[n] = s[t];
}

// per-bucket CSR fill: LDS scatter (pad slots -> dummy node n), write rptr + colx
__global__ __launch_bounds__(256) void k_bfill(const unsigned* __restrict__ bpair,
                                               const int* __restrict__ gbase0,
                                               const int* __restrict__ gcount,
                                               const int* __restrict__ pbase,
                                               const int* __restrict__ lofs,
                                               const int* __restrict__ psum,
                                               int* __restrict__ rptr,
                                               int* __restrict__ colx, int n) {
    __shared__ int cur[BNODES];
    __shared__ int lcol[CAP];
    int b = blockIdx.x, t = threadIdx.x;
    int first = b << BSH;
    int base = pbase[b];
    int tot = min(psum[b], CAP);
    int lim = min(BNODES, n - first);
    for (int q = t; q < lim; q += 256) {
        int lo = lofs[first + q];
        cur[q] = lo;
        rptr[first + q] = base + lo;
    }
    for (int p = t; p < tot; p += 256) lcol[p] = n;
    __syncthreads();
    int gs = gbase0[b], ge = gs + gcount[b];
    for (int e = gs + t; e < ge; e += 256) {
        unsigned w = bpair[e];
        int lpos = atomicAdd(&cur[w & (BNODES - 1)], 1);
        if (lpos < CAP) lcol[lpos] = (int)(w >> BSH);
    }
    __syncthreads();
    for (int p = t; p < tot; p += 256) colx[base + p] = lcol[p];
}

// ---------------- W split: whT/wlT[n][k] bf16 (transposed), per layer ----------------

__global__ void k_wsplit(const float* __restrict__ W1, const float* __restrict__ W2,
                         const float* __restrict__ W3,
                         unsigned short* __restrict__ wh, unsigned short* __restrict__ wl) {
    int idx = blockIdx.x * 256 + threadIdx.x;     // 0..49151
    int l = idx >> 14;
    int r = idx & 16383;
    int k = r >> 7, nn = r & 127;
    const float* W = (l == 0) ? W1 : (l == 1) ? W2 : W3;
    float a = W[k * 128 + nn];
    unsigned ab = __float_as_uint(a);
    unsigned hb = (ab + 0x7fffu + ((ab >> 16) & 1)) & 0xffff0000u;
    float res = a - __uint_as_float(hb);
    unsigned rb = __float_as_uint(res);
    unsigned lb = (rb + 0x7fffu + ((rb >> 16) & 1)) >> 16;
    wh[l * 16384 + nn * 128 + k] = (unsigned short)(hb >> 16);
    wl[l * 16384 + nn * 128 + k] = (unsigned short)lb;
}

// ---------------- split-bf16 MFMA GEMM: HHc[8 planes of 16] = scale * (A @ W) --------
// C = ah*wh + ah*wl + al*wh (al*wl dropped, ~2^-18 rel).
// LDS rows padded to 36 shorts (72 B stride): 16-lane b64 reads hit banks
// (18*row)%32 = all-distinct -> conflict-free; 8 B alignment preserved.

#define LPAD 36

__device__ __forceinline__ s16x8 ld_frag(const unsigned short* row, int klo) {
    union { u64 d[2]; s16x8 v; } u;
    u.d[0] = *(const u64*)(row + klo);
    u.d[1] = *(const u64*)(row + klo + 16);
    return u.v;
}

__device__ __forceinline__ void bf16split(float a, unsigned& h, unsigned& lo) {
    unsigned ab = __float_as_uint(a);
    unsigned hb = (ab + 0x7fffu + ((ab >> 16) & 1)) & 0xffff0000u;
    float res = a - __uint_as_float(hb);
    unsigned rb = __float_as_uint(res);
    h  = hb >> 16;
    lo = (rb + 0x7fffu + ((rb >> 16) & 1)) >> 16;
}

template<int AL>
__global__ __launch_bounds__(256) void k_gemm(const float* __restrict__ A,
                                              const float* __restrict__ actD,
                                              const float* __restrict__ actS,
                                              const unsigned short* __restrict__ whT,
                                              const unsigned short* __restrict__ wlT,
                                              const float* __restrict__ scale,
                                              float* __restrict__ HHc,
                                              int M, size_t PSH, size_t PSA) {
    __shared__ unsigned short Ah[128][LPAD], Al[128][LPAD];
    __shared__ unsigned short Wh[128][LPAD], Wl[128][LPAD];
    int tid = threadIdx.x;
    int w = tid >> 6, l = tid & 63;
    int bm = blockIdx.x * 128;
    vflt4 acc[2][8] = {};

    for (int kc = 0; kc < 128; kc += 32) {
        // stage A chunk -> Ah/Al (bf16 split, packed u64 stores)
        #pragma unroll
        for (int it = 0; it < 4; ++it) {
            int idx = it * 256 + tid;
            int row = idx >> 3, kseg = (idx & 7) * 4;
            int grow = bm + row;
            vflt4 v = {0.f, 0.f, 0.f, 0.f};
            if (grow < M) {
                if (AL == 0) {
                    v = *(const vflt4*)(A + (size_t)grow * 128 + kc + kseg);
                } else {
                    int kcol = kc + kseg;
                    int pl = kcol >> 4;
                    const float* ab = (pl < 7) ? (actD + (size_t)pl * PSA) : actS;
                    v = *(const vflt4*)(ab + (size_t)grow * 16 + (kcol & 15));
                }
            }
            u64 hword = 0, lword = 0;
            #pragma unroll
            for (int j = 0; j < 4; ++j) {
                unsigned h, lo;
                bf16split(v[j], h, lo);
                hword |= (u64)h  << (16 * j);
                lword |= (u64)lo << (16 * j);
            }
            *(u64*)&Ah[row][kseg] = hword;
            *(u64*)&Al[row][kseg] = lword;
        }
        // stage W chunk (pre-split, [n][k] layout) -> Wh/Wl
        #pragma unroll
        for (int it = 0; it < 4; ++it) {
            int idx = it * 256 + tid;
            int nn = idx >> 3, kseg = (idx & 7) * 4;
            *(u64*)&Wh[nn][kseg] = *(const u64*)(whT + nn * 128 + kc + kseg);
            *(u64*)&Wl[nn][kseg] = *(const u64*)(wlT + nn * 128 + kc + kseg);
        }
        __syncthreads();

        int klo = (l >> 4) * 4;
        s16x8 ah0 = ld_frag(Ah[w * 32 + (l & 15)],      klo);
        s16x8 ah1 = ld_frag(Ah[w * 32 + 16 + (l & 15)], klo);
        s16x8 al0 = ld_frag(Al[w * 32 + (l & 15)],      klo);
        s16x8 al1 = ld_frag(Al[w * 32 + 16 + (l & 15)], klo);
        #pragma unroll
        for (int tn = 0; tn < 8; ++tn) {
            s16x8 whf = ld_frag(Wh[tn * 16 + (l & 15)], klo);
            s16x8 wlf = ld_frag(Wl[tn * 16 + (l & 15)], klo);
            acc[0][tn] = __builtin_amdgcn_mfma_f32_16x16x32_bf16(ah0, whf, acc[0][tn], 0, 0, 0);
            acc[0][tn] = __builtin_amdgcn_mfma_f32_16x16x32_bf16(ah0, wlf, acc[0][tn], 0, 0, 0);
            acc[0][tn] = __builtin_amdgcn_mfma_f32_16x16x32_bf16(al0, whf, acc[0][tn], 0, 0, 0);
            acc[1][tn] = __builtin_amdgcn_mfma_f32_16x16x32_bf16(ah1, whf, acc[1][tn], 0, 0, 0);
            acc[1][tn] = __builtin_amdgcn_mfma_f32_16x16x32_bf16(ah1, wlf, acc[1][tn], 0, 0, 0);
            acc[1][tn] = __builtin_amdgcn_mfma_f32_16x16x32_bf16(al1, whf, acc[1][tn], 0, 0, 0);
        }
        __syncthreads();
    }
    // epilogue: tile (tm,tn): row = bm + w*32 + tm*16 + (l>>4)*4 + r, col = tn*16 + (l&15)
    #pragma unroll
    for (int tm = 0; tm < 2; ++tm) {
        #pragma unroll
        for (int tn = 0; tn < 8; ++tn) {
            float* ob = HHc + (size_t)tn * PSH + (l & 15);
            #pragma unroll
            for (int r = 0; r < 4; ++r) {
                int grow = bm + w * 32 + tm * 16 + (l >> 4) * 4 + r;
                if (grow < M) {
                    ob[(size_t)grow * 16] = acc[tm][tn][r] * scale[grow];
                }
            }
        }
    }
}

// ---------------- SpMM aggregate, 16-col feature chunks, XCD-bound (R6 design) --------

template<int FINAL>
__global__ __launch_bounds__(256) void k_spmm(const float* __restrict__ HHc,
                                              const int* __restrict__ colx,
                                              const int* __restrict__ rptr,
                                              const float* __restrict__ dinv,
                                              const float* __restrict__ bias,
                                              float* __restrict__ actD,
                                              float* __restrict__ actS,
                                              float* __restrict__ out,
                                              int n, size_t PSH, size_t PSA, int do_relu) {
    int chunk = blockIdx.x & 7;
    int node  = (blockIdx.x >> 3) * 16 + (threadIdx.x >> 4);
    int ll    = threadIdx.x & 15;
    if (node >= n) return;
    const float* plane = HHc + (size_t)chunk * PSH;
    int e  = rptr[node];
    int e1 = rptr[node + 1];
    float acc = 0.f;
    #pragma unroll 2
    for (; e < e1; e += 4) {
        vint4 s = *(const vint4*)(colx + e);
        float h0 = plane[(size_t)s.x * 16 + ll];
        float h1 = plane[(size_t)s.y * 16 + ll];
        float h2 = plane[(size_t)s.z * 16 + ll];
        float h3 = plane[(size_t)s.w * 16 + ll];
        acc += (h0 + h1) + (h2 + h3);
    }
    float o = fmaf(dinv[node], acc, bias[chunk * 16 + ll]);
    if (do_relu) o = fmaxf(o, 0.f);
    if (FINAL) {
        out[(size_t)node * 128 + chunk * 16 + ll] = o;
    } else {
        float* ob = (chunk < 7) ? (actD + (size_t)chunk * PSA) : actS;
        ob[(size_t)node * 16 + ll] = o;
    }
}

// ---------------- host ----------------

extern "C" void kernel_launch(void* const* d_in, const int* in_sizes, int n_in,
                              void* d_out, int out_size, void* d_ws, size_t ws_size,
                              hipStream_t stream) {
    const float* x  = (const float*)d_in[0];
    const int*   ei = (const int*)d_in[1];
    const float* W1 = (const float*)d_in[2];
    const float* b1 = (const float*)d_in[3];
    const float* W2 = (const float*)d_in[4];
    const float* b2 = (const float*)d_in[5];
    const float* W3 = (const float*)d_in[6];
    const float* b3 = (const float*)d_in[7];
    float* out = (float*)d_out;

    const int n = in_sizes[0] / N_HID;         // 100000
    const int E = in_sizes[1] / 2;             // 1600000
    const long T = (long)E + n;
    const size_t PSH = (size_t)(n + 1) * 16;   // HHc plane stride (dummy row n)
    const size_t PSA = (size_t)n * 16;         // ACT plane stride

    const int* src = ei;
    const int* dst = ei + E;

    size_t off = 0;
    auto alloc = [&](size_t bytes) {
        size_t o = off;
        off += (bytes + 255) & ~(size_t)255;
        return (char*)d_ws + o;
    };
    float* dinv   = (float*)alloc((size_t)n * 4);
    int*   rptr   = (int*)  alloc((size_t)(n + 1) * 4);
    int*   lofs   = (int*)  alloc((size_t)n * 4);
    int*   gcount = (int*)  alloc(1024);
    int*   gbase0 = (int*)  alloc(1024);
    int*   gcur   = (int*)  alloc(1024);
    int*   psum   = (int*)  alloc(1024);
    int*   pbase  = (int*)  alloc(1024);
    unsigned short* whT = (unsigned short*)alloc(3 * 16384 * 2);
    unsigned short* wlT = (unsigned short*)alloc(3 * 16384 * 2);
    int*   colx   = (int*)  alloc((size_t)(T + 3 * (size_t)n + 64) * 4);
    float* actS   = (float*)alloc(PSA * 4);        // ACT spill plane (chunk 7)
    float* HHc    = (float*)alloc(PSH * 8 * 4);    // 8 chunked GEMM-output planes
    // bpair (u32, 6.8 MB) aliases HHc front (consumed by k_bfill before gemm1)
    unsigned* bpair = (unsigned*)HHc;
    float* actD = out;   // ACT planes 0-6 staged in d_out
    (void)ws_size;

    const int NBK  = (n + BNODES - 1) >> BSH;          // 196 buckets
    const int ABLK = (int)((T + CHUNK - 1) / CHUNK);   // 416 chunks

    k_init<<<2, 256, 0, stream>>>(gcount, NBK, HHc, n, PSH);
    k_wsplit<<<192, 256, 0, stream>>>(W1, W2, W3, whT, wlT);
    k_bcount<<<ABLK, 256, 0, stream>>>(dst, E, n, gcount);
    k_bscan<<<1, 256, 0, stream>>>(gcount, gbase0, gcur, NBK);
    k_bucket<<<ABLK, 256, 0, stream>>>(src, dst, E, n, gcur, bpair);
    k_bdeg<<<NBK, 256, 0, stream>>>(bpair, gbase0, gcount, dinv, lofs, psum, n);
    k_pscan<<<1, 256, 0, stream>>>(psum, pbase, rptr, n, NBK);
    k_bfill<<<NBK, 256, 0, stream>>>(bpair, gbase0, gcount, pbase, lofs, psum, rptr, colx, n);
    // re-zero HHc dummy rows (bpair alias clobbered them)
    k_init<<<2, 256, 0, stream>>>(gcount, 0, HHc, n, PSH);

    int gblk = (n + 127) / 128;
    int sblk = 8 * ((n + 15) / 16);   // 8 chunks x node groups of 16

    k_gemm<0><<<gblk, 256, 0, stream>>>(x, nullptr, nullptr, whT, wlT, dinv, HHc, n, PSH, PSA);
    k_spmm<0><<<sblk, 256, 0, stream>>>(HHc, colx, rptr, dinv, b1, actD, actS, out, n, PSH, PSA, 1);
    k_gemm<1><<<gblk, 256, 0, stream>>>(nullptr, actD, actS, whT + 16384, wlT + 16384, dinv, HHc, n, PSH, PSA);
    k_spmm<0><<<sblk, 256, 0, stream>>>(HHc, colx, rptr, dinv, b2, actD, actS, out, n, PSH, PSA, 1);
    k_gemm<1><<<gblk, 256, 0, stream>>>(nullptr, actD, actS, whT + 32768, wlT + 32768, dinv, HHc, n, PSH, PSA);
    k_spmm<1><<<sblk, 256, 0, stream>>>(HHc, colx, rptr, dinv, b3, actD, actS, out, n, PSH, PSA, 0);
}

// Round 10
// 517.688 us; speedup vs baseline: 1.3807x; 1.1070x over previous
//
#include <hip/hip_runtime.h>
#include <hip/hip_bf16.h>

#define N_HID 128
#define BSH 9
#define BNODES 512          // nodes per bucket (1 << BSH)
#define CAP 14848           // LDS colx staging cap per bucket (58 KB)
#define CHUNK 4096          // edges per k_bucket block
#define QSCALE 4096.0f      // int16 fixed-point scale for H planes

typedef int      vint4  __attribute__((ext_vector_type(4)));
typedef float    vflt4  __attribute__((ext_vector_type(4)));
typedef short    s16x8  __attribute__((ext_vector_type(8)));
typedef unsigned long long u64;

// ---------------- bucketed CSR build ----------------

// block 0: zero gcount; block 1: zero dummy row n of all 8 int16 HHi planes
__global__ void k_init(int* gcount, int nbk, short* HHi, int n, size_t PSH) {
    int t = threadIdx.x;
    if (blockIdx.x == 0) {
        if (t < nbk) gcount[t] = 0;
    } else {
        if (t < 128) {  // 8 planes x 16 lanes
            int p = t >> 4, l = t & 15;
            HHi[(size_t)p * PSH + (size_t)n * 16 + l] = 0;
        }
    }
}

// count edges per dst-bucket (LDS-privatized)
__global__ __launch_bounds__(256) void k_bcount(const int* __restrict__ dst,
                                                int E, int n, int* __restrict__ gcount) {
    __shared__ int hist[256];
    int t = threadIdx.x;
    hist[t] = 0;
    __syncthreads();
    long base = (long)blockIdx.x * CHUNK;
    long T = (long)E + n;
    int cnt = (int)min((long)CHUNK, T - base);
    for (int j = t; j < cnt; j += 256) {
        long i = base + j;
        int d = (i < E) ? dst[i] : (int)(i - E);
        atomicAdd(&hist[d >> BSH], 1);
    }
    __syncthreads();
    if (hist[t] > 0) atomicAdd(&gcount[t], hist[t]);
}

// exclusive scan of bucket counts -> gbase0, init gcur
__global__ void k_bscan(const int* __restrict__ gcount, int* __restrict__ gbase0,
                        int* __restrict__ gcur, int nbk) {
    __shared__ int s[256];
    int t = threadIdx.x;
    int v = (t < nbk) ? gcount[t] : 0;
    s[t] = v;
    __syncthreads();
    for (int off = 1; off < 256; off <<= 1) {
        int y = (t >= off) ? s[t - off] : 0;
        __syncthreads();
        s[t] += y;
        __syncthreads();
    }
    if (t < nbk) { gbase0[t] = s[t] - v; gcur[t] = s[t] - v; }
}

// partition edges into bucket-contiguous bpair[] (packed u32: src<<9 | dst_local)
__global__ __launch_bounds__(256) void k_bucket(const int* __restrict__ src,
                                                const int* __restrict__ dst,
                                                int E, int n, int* __restrict__ gcur,
                                                unsigned* __restrict__ bpair) {
    __shared__ int hist[256];
    __shared__ int incl[256];
    __shared__ int loff[256];
    __shared__ int gb[256];
    __shared__ unsigned lp[CHUNK];
    __shared__ unsigned char pb[CHUNK];
    int t = threadIdx.x;
    hist[t] = 0;
    __syncthreads();
    long base = (long)blockIdx.x * CHUNK;
    long T = (long)E + n;
    int cnt = (int)min((long)CHUNK, T - base);

    unsigned w_[16];
    int b_[16], r_[16];
    #pragma unroll
    for (int u = 0; u < 16; ++u) {
        int j = t + u * 256;
        if (j < cnt) {
            long i = base + j;
            int s, d;
            if (i < E) { s = src[i]; d = dst[i]; } else { s = (int)(i - E); d = s; }
            w_[u] = ((unsigned)s << BSH) | (unsigned)(d & (BNODES - 1));
            b_[u] = d >> BSH;
            r_[u] = atomicAdd(&hist[b_[u]], 1);
        } else { w_[u] = 0; b_[u] = 0; r_[u] = -1; }
    }
    __syncthreads();
    incl[t] = hist[t];
    __syncthreads();
    for (int off = 1; off < 256; off <<= 1) {
        int y = (t >= off) ? incl[t - off] : 0;
        __syncthreads();
        incl[t] += y;
        __syncthreads();
    }
    loff[t] = incl[t] - hist[t];
    if (hist[t] > 0) gb[t] = atomicAdd(&gcur[t], hist[t]);
    __syncthreads();
    #pragma unroll
    for (int u = 0; u < 16; ++u) {
        if (r_[u] >= 0) {
            int p = loff[b_[u]] + r_[u];
            lp[p] = w_[u];
            pb[p] = (unsigned char)b_[u];
        }
    }
    __syncthreads();
    for (int p = t; p < cnt; p += 256) {
        int b = pb[p];
        bpair[(size_t)gb[b] + (p - loff[b])] = lp[p];
    }
}

// per-bucket: degree hist -> dinv, local padded-offset scan -> lofs, bucket total -> psum
__global__ __launch_bounds__(256) void k_bdeg(const unsigned* __restrict__ bpair,
                                              const int* __restrict__ gbase0,
                                              const int* __restrict__ gcount,
                                              float* __restrict__ dinv,
                                              int* __restrict__ lofs,
                                              int* __restrict__ psum, int n) {
    __shared__ int hist[BNODES];
    __shared__ int sc[256];
    int b = blockIdx.x, t = threadIdx.x;
    hist[t] = 0; hist[t + 256] = 0;
    __syncthreads();
    int gs = gbase0[b], ge = gs + gcount[b];
    for (int e = gs + t; e < ge; e += 256)
        atomicAdd(&hist[bpair[e] & (BNODES - 1)], 1);
    __syncthreads();
    int q0 = 2 * t, q1 = 2 * t + 1;
    int p0 = (hist[q0] + 3) & ~3;
    int p1 = (hist[q1] + 3) & ~3;
    int pair = p0 + p1;
    sc[t] = pair;
    __syncthreads();
    for (int off = 1; off < 256; off <<= 1) {
        int y = (t >= off) ? sc[t - off] : 0;
        __syncthreads();
        sc[t] += y;
        __syncthreads();
    }
    int excl = sc[t] - pair;
    int first = b << BSH;
    if (first + q0 < n) {
        lofs[first + q0] = excl;
        dinv[first + q0] = rsqrtf((float)hist[q0]);
    }
    if (first + q1 < n) {
        lofs[first + q1] = excl + p0;
        dinv[first + q1] = rsqrtf((float)hist[q1]);
    }
    if (t == 255) psum[b] = sc[255];
}

// scan bucket padded totals -> pbase; write rptr[n]
__global__ void k_pscan(const int* __restrict__ psum, int* __restrict__ pbase,
                        int* __restrict__ rptr, int n, int nbk) {
    __shared__ int s[256];
    int t = threadIdx.x;
    int v = (t < nbk) ? psum[t] : 0;
    s[t] = v;
    __syncthreads();
    for (int off = 1; off < 256; off <<= 1) {
        int y = (t >= off) ? s[t - off] : 0;
        __syncthreads();
        s[t] += y;
        __syncthreads();
    }
    if (t < nbk) pbase[t] = s[t] - v;
    if (t == nbk - 1) rptr[n] = s[t];
}

// per-bucket CSR fill: LDS scatter (pad slots -> dummy node n), write rptr + colx
__global__ __launch_bounds__(256) void k_bfill(const unsigned* __restrict__ bpair,
                                               const int* __restrict__ gbase0,
                                               const int* __restrict__ gcount,
                                               const int* __restrict__ pbase,
                                               const int* __restrict__ lofs,
                                               const int* __restrict__ psum,
                                               int* __restrict__ rptr,
                                               int* __restrict__ colx, int n) {
    __shared__ int cur[BNODES];
    __shared__ int lcol[CAP];
    int b = blockIdx.x, t = threadIdx.x;
    int first = b << BSH;
    int base = pbase[b];
    int tot = min(psum[b], CAP);
    int lim = min(BNODES, n - first);
    for (int q = t; q < lim; q += 256) {
        int lo = lofs[first + q];
        cur[q] = lo;
        rptr[first + q] = base + lo;
    }
    for (int p = t; p < tot; p += 256) lcol[p] = n;
    __syncthreads();
    int gs = gbase0[b], ge = gs + gcount[b];
    for (int e = gs + t; e < ge; e += 256) {
        unsigned w = bpair[e];
        int lpos = atomicAdd(&cur[w & (BNODES - 1)], 1);
        if (lpos < CAP) lcol[lpos] = (int)(w >> BSH);
    }
    __syncthreads();
    for (int p = t; p < tot; p += 256) colx[base + p] = lcol[p];
}

// ---------------- W split: whT/wlT[n][k] bf16 (transposed), per layer ----------------

__global__ void k_wsplit(const float* __restrict__ W1, const float* __restrict__ W2,
                         const float* __restrict__ W3,
                         unsigned short* __restrict__ wh, unsigned short* __restrict__ wl) {
    int idx = blockIdx.x * 256 + threadIdx.x;     // 0..49151
    int l = idx >> 14;
    int r = idx & 16383;
    int k = r >> 7, nn = r & 127;
    const float* W = (l == 0) ? W1 : (l == 1) ? W2 : W3;
    float a = W[k * 128 + nn];
    unsigned ab = __float_as_uint(a);
    unsigned hb = (ab + 0x7fffu + ((ab >> 16) & 1)) & 0xffff0000u;
    float res = a - __uint_as_float(hb);
    unsigned rb = __float_as_uint(res);
    unsigned lb = (rb + 0x7fffu + ((rb >> 16) & 1)) >> 16;
    wh[l * 16384 + nn * 128 + k] = (unsigned short)(hb >> 16);
    wl[l * 16384 + nn * 128 + k] = (unsigned short)lb;
}

// ---------------- split-bf16 MFMA GEMM: HHi[8 int16 planes of 16] = scale*(A@W)*4096 ----
// C = ah*wh + ah*wl + al*wh (al*wl dropped).  LDS rows padded to 36 shorts -> conflict-free.

#define LPAD 36

__device__ __forceinline__ s16x8 ld_frag(const unsigned short* row, int klo) {
    union { u64 d[2]; s16x8 v; } u;
    u.d[0] = *(const u64*)(row + klo);
    u.d[1] = *(const u64*)(row + klo + 16);
    return u.v;
}

__device__ __forceinline__ void bf16split(float a, unsigned& h, unsigned& lo) {
    unsigned ab = __float_as_uint(a);
    unsigned hb = (ab + 0x7fffu + ((ab >> 16) & 1)) & 0xffff0000u;
    float res = a - __uint_as_float(hb);
    unsigned rb = __float_as_uint(res);
    h  = hb >> 16;
    lo = (rb + 0x7fffu + ((rb >> 16) & 1)) >> 16;
}

template<int AL>
__global__ __launch_bounds__(256) void k_gemm(const float* __restrict__ A,
                                              const float* __restrict__ actD,
                                              const float* __restrict__ actS,
                                              const unsigned short* __restrict__ whT,
                                              const unsigned short* __restrict__ wlT,
                                              const float* __restrict__ scale,
                                              short* __restrict__ HHi,
                                              int M, size_t PSH, size_t PSA) {
    __shared__ unsigned short Ah[128][LPAD], Al[128][LPAD];
    __shared__ unsigned short Wh[128][LPAD], Wl[128][LPAD];
    int tid = threadIdx.x;
    int w = tid >> 6, l = tid & 63;
    int bm = blockIdx.x * 128;
    vflt4 acc[2][8] = {};

    for (int kc = 0; kc < 128; kc += 32) {
        // stage A chunk -> Ah/Al (bf16 split, packed u64 stores)
        #pragma unroll
        for (int it = 0; it < 4; ++it) {
            int idx = it * 256 + tid;
            int row = idx >> 3, kseg = (idx & 7) * 4;
            int grow = bm + row;
            vflt4 v = {0.f, 0.f, 0.f, 0.f};
            if (grow < M) {
                if (AL == 0) {
                    v = *(const vflt4*)(A + (size_t)grow * 128 + kc + kseg);
                } else {
                    int kcol = kc + kseg;
                    int pl = kcol >> 4;
                    const float* ab = (pl < 7) ? (actD + (size_t)pl * PSA) : actS;
                    v = *(const vflt4*)(ab + (size_t)grow * 16 + (kcol & 15));
                }
            }
            u64 hword = 0, lword = 0;
            #pragma unroll
            for (int j = 0; j < 4; ++j) {
                unsigned h, lo;
                bf16split(v[j], h, lo);
                hword |= (u64)h  << (16 * j);
                lword |= (u64)lo << (16 * j);
            }
            *(u64*)&Ah[row][kseg] = hword;
            *(u64*)&Al[row][kseg] = lword;
        }
        // stage W chunk (pre-split, [n][k] layout) -> Wh/Wl
        #pragma unroll
        for (int it = 0; it < 4; ++it) {
            int idx = it * 256 + tid;
            int nn = idx >> 3, kseg = (idx & 7) * 4;
            *(u64*)&Wh[nn][kseg] = *(const u64*)(whT + nn * 128 + kc + kseg);
            *(u64*)&Wl[nn][kseg] = *(const u64*)(wlT + nn * 128 + kc + kseg);
        }
        __syncthreads();

        int klo = (l >> 4) * 4;
        s16x8 ah0 = ld_frag(Ah[w * 32 + (l & 15)],      klo);
        s16x8 ah1 = ld_frag(Ah[w * 32 + 16 + (l & 15)], klo);
        s16x8 al0 = ld_frag(Al[w * 32 + (l & 15)],      klo);
        s16x8 al1 = ld_frag(Al[w * 32 + 16 + (l & 15)], klo);
        #pragma unroll
        for (int tn = 0; tn < 8; ++tn) {
            s16x8 whf = ld_frag(Wh[tn * 16 + (l & 15)], klo);
            s16x8 wlf = ld_frag(Wl[tn * 16 + (l & 15)], klo);
            acc[0][tn] = __builtin_amdgcn_mfma_f32_16x16x32_bf16(ah0, whf, acc[0][tn], 0, 0, 0);
            acc[0][tn] = __builtin_amdgcn_mfma_f32_16x16x32_bf16(ah0, wlf, acc[0][tn], 0, 0, 0);
            acc[0][tn] = __builtin_amdgcn_mfma_f32_16x16x32_bf16(al0, whf, acc[0][tn], 0, 0, 0);
            acc[1][tn] = __builtin_amdgcn_mfma_f32_16x16x32_bf16(ah1, whf, acc[1][tn], 0, 0, 0);
            acc[1][tn] = __builtin_amdgcn_mfma_f32_16x16x32_bf16(ah1, wlf, acc[1][tn], 0, 0, 0);
            acc[1][tn] = __builtin_amdgcn_mfma_f32_16x16x32_bf16(al1, whf, acc[1][tn], 0, 0, 0);
        }
        __syncthreads();
    }
    // epilogue: quantize to int16 (scale*4096, clamp) into plane tn
    #pragma unroll
    for (int tm = 0; tm < 2; ++tm) {
        #pragma unroll
        for (int tn = 0; tn < 8; ++tn) {
            short* ob = HHi + (size_t)tn * PSH + (l & 15);
            #pragma unroll
            for (int r = 0; r < 4; ++r) {
                int grow = bm + w * 32 + tm * 16 + (l >> 4) * 4 + r;
                if (grow < M) {
                    float vq = acc[tm][tn][r] * scale[grow] * QSCALE;
                    int q = __float2int_rn(vq);
                    q = min(max(q, -32767), 32767);
                    ob[(size_t)grow * 16] = (short)q;
                }
            }
        }
    }
}

// ---------------- SpMM aggregate, int16 planes (3.2 MB, L2-resident), XCD-bound --------
// chunk = blockIdx&7 -> plane per XCD. 16 lanes/node, 2B gathers (32 B/edge request).
// Exact int32 accumulate; scale once at the end. FINAL: row-major f32 out.

template<int FINAL>
__global__ __launch_bounds__(256) void k_spmm(const short* __restrict__ HHi,
                                              const int* __restrict__ colx,
                                              const int* __restrict__ rptr,
                                              const float* __restrict__ dinv,
                                              const float* __restrict__ bias,
                                              float* __restrict__ actD,
                                              float* __restrict__ actS,
                                              float* __restrict__ out,
                                              int n, size_t PSH, size_t PSA, int do_relu) {
    int chunk = blockIdx.x & 7;
    int node  = (blockIdx.x >> 3) * 16 + (threadIdx.x >> 4);
    int ll    = threadIdx.x & 15;
    if (node >= n) return;
    const short* plane = HHi + (size_t)chunk * PSH;
    int e  = rptr[node];
    int e1 = rptr[node + 1];
    int acc = 0;
    #pragma unroll 2
    for (; e < e1; e += 4) {
        vint4 s = *(const vint4*)(colx + e);
        int h0 = plane[(size_t)s.x * 16 + ll];
        int h1 = plane[(size_t)s.y * 16 + ll];
        int h2 = plane[(size_t)s.z * 16 + ll];
        int h3 = plane[(size_t)s.w * 16 + ll];
        acc += (h0 + h1) + (h2 + h3);
    }
    float o = fmaf(dinv[node] * (1.0f / QSCALE), (float)acc, bias[chunk * 16 + ll]);
    if (do_relu) o = fmaxf(o, 0.f);
    if (FINAL) {
        out[(size_t)node * 128 + chunk * 16 + ll] = o;
    } else {
        float* ob = (chunk < 7) ? (actD + (size_t)chunk * PSA) : actS;
        ob[(size_t)node * 16 + ll] = o;
    }
}

// ---------------- host ----------------

extern "C" void kernel_launch(void* const* d_in, const int* in_sizes, int n_in,
                              void* d_out, int out_size, void* d_ws, size_t ws_size,
                              hipStream_t stream) {
    const float* x  = (const float*)d_in[0];
    const int*   ei = (const int*)d_in[1];
    const float* W1 = (const float*)d_in[2];
    const float* b1 = (const float*)d_in[3];
    const float* W2 = (const float*)d_in[4];
    const float* b2 = (const float*)d_in[5];
    const float* W3 = (const float*)d_in[6];
    const float* b3 = (const float*)d_in[7];
    float* out = (float*)d_out;

    const int n = in_sizes[0] / N_HID;         // 100000
    const int E = in_sizes[1] / 2;             // 1600000
    const long T = (long)E + n;
    const size_t PSH = (size_t)(n + 1) * 16;   // HHi plane stride in shorts (dummy row n)
    const size_t PSA = (size_t)n * 16;         // ACT plane stride (f32)

    const int* src = ei;
    const int* dst = ei + E;

    size_t off = 0;
    auto alloc = [&](size_t bytes) {
        size_t o = off;
        off += (bytes + 255) & ~(size_t)255;
        return (char*)d_ws + o;
    };
    float* dinv   = (float*)alloc((size_t)n * 4);
    int*   rptr   = (int*)  alloc((size_t)(n + 1) * 4);
    int*   lofs   = (int*)  alloc((size_t)n * 4);
    int*   gcount = (int*)  alloc(1024);
    int*   gbase0 = (int*)  alloc(1024);
    int*   gcur   = (int*)  alloc(1024);
    int*   psum   = (int*)  alloc(1024);
    int*   pbase  = (int*)  alloc(1024);
    unsigned short* whT = (unsigned short*)alloc(3 * 16384 * 2);
    unsigned short* wlT = (unsigned short*)alloc(3 * 16384 * 2);
    int*   colx   = (int*)  alloc((size_t)(T + 3 * (size_t)n + 64) * 4);
    float* actS   = (float*)alloc(PSA * 4);        // ACT spill plane (chunk 7)
    short* HHi    = (short*)alloc(PSH * 8 * 2);    // 8 int16 GEMM-output planes (25.6 MB)
    // bpair (u32, 6.8 MB) aliases HHi front (consumed by k_bfill before gemm1)
    unsigned* bpair = (unsigned*)HHi;
    float* actD = out;   // ACT planes 0-6 staged in d_out
    (void)ws_size;

    const int NBK  = (n + BNODES - 1) >> BSH;          // 196 buckets
    const int ABLK = (int)((T + CHUNK - 1) / CHUNK);   // 416 chunks

    k_init<<<2, 256, 0, stream>>>(gcount, NBK, HHi, n, PSH);
    k_wsplit<<<192, 256, 0, stream>>>(W1, W2, W3, whT, wlT);
    k_bcount<<<ABLK, 256, 0, stream>>>(dst, E, n, gcount);
    k_bscan<<<1, 256, 0, stream>>>(gcount, gbase0, gcur, NBK);
    k_bucket<<<ABLK, 256, 0, stream>>>(src, dst, E, n, gcur, bpair);
    k_bdeg<<<NBK, 256, 0, stream>>>(bpair, gbase0, gcount, dinv, lofs, psum, n);
    k_pscan<<<1, 256, 0, stream>>>(psum, pbase, rptr, n, NBK);
    k_bfill<<<NBK, 256, 0, stream>>>(bpair, gbase0, gcount, pbase, lofs, psum, rptr, colx, n);
    // re-zero HHi dummy rows (bpair alias clobbered them)
    k_init<<<2, 256, 0, stream>>>(gcount, 0, HHi, n, PSH);

    int gblk = (n + 127) / 128;
    int sblk = 8 * ((n + 15) / 16);   // 8 chunks x node groups of 16

    k_gemm<0><<<gblk, 256, 0, stream>>>(x, nullptr, nullptr, whT, wlT, dinv, HHi, n, PSH, PSA);
    k_spmm<0><<<sblk, 256, 0, stream>>>(HHi, colx, rptr, dinv, b1, actD, actS, out, n, PSH, PSA, 1);
    k_gemm<1><<<gblk, 256, 0, stream>>>(nullptr, actD, actS, whT + 16384, wlT + 16384, dinv, HHi, n, PSH, PSA);
    k_spmm<0><<<sblk, 256, 0, stream>>>(HHi, colx, rptr, dinv, b2, actD, actS, out, n, PSH, PSA, 1);
    k_gemm<1><<<gblk, 256, 0, stream>>>(nullptr, actD, actS, whT + 32768, wlT + 32768, dinv, HHi, n, PSH, PSA);
    k_spmm<1><<<sblk, 256, 0, stream>>>(HHi, colx, rptr, dinv, b3, actD, actS, out, n, PSH, PSA, 0);
}